// Round 11
// baseline (1760.720 us; speedup 1.0000x reference)
//
#include <hip/hip_runtime.h>
#include <hip/hip_bf16.h>

// Elman RNN, persistent kernel v8 = r6 structure (2 independent blocks/CU)
//                                   x r9 protocol (asm sc0sc1 + rule-#18 fence).
// h_t = tanh([h_{t-1} | x_t] @ [Wh|Wi]^T + (Wh_b+Wi_b)); out = h_T @ Wo^T + Wo_b
// T=128, B=512, E=256, H=1024, O=256.
//
// 32 groups x 16 rows; group = 16 blocks (64 cols each). 512 blocks, 2/CU
// (LDS 40KB, VGPR<=128): a CU's two blocks come from different groups, so one
// block's full-step compute hides the other's poll/stage latency (hardware
// wave interleave — the overlap r10's software version couldn't deliver).
//
// Protocol lessons (measured):
//  r2: RELEASE/agent atomics -> per-step L2 writeback flush. Never.
//  r4/5/9: asm sc0 sc1 loads/stores: h+flags served by L2/MALL, FETCH ~107MB.
//  r6: asm load + waitcnt + register-only consumer races unless followed by
//      sched_barrier(0) (rule #18). THE r6 bug, fixed in r9's poll.
//  r7/r8: compiler AGENT/SYSTEM atomic polls -> MALL/HBM storms (FETCH 4-5x).

#define T_ 128
#define B_ 512
#define E_ 256
#define H_ 1024
#define O_ 256
#define RG 16            // rows per group
#define HB (B_ * H_)     // elems per h slot (1 MB bf16)

typedef __bf16 bf16x8 __attribute__((ext_vector_type(8)));
typedef float  f32x2  __attribute__((ext_vector_type(2)));
typedef float  f32x4  __attribute__((ext_vector_type(4)));
typedef unsigned int u32x4 __attribute__((ext_vector_type(4)));

static __device__ __forceinline__ unsigned short f2bf(float f) {
  unsigned u = __float_as_uint(f);
  u += 0x7fff + ((u >> 16) & 1);  // RNE
  return (unsigned short)(u >> 16);
}
static __device__ __forceinline__ unsigned pk2(float a, float b) {
  return (unsigned)f2bf(a) | ((unsigned)f2bf(b) << 16);
}
static __device__ __forceinline__ bf16x8 cvt8(const float* p) {
  float4 f0 = reinterpret_cast<const float4*>(p)[0];
  float4 f1 = reinterpret_cast<const float4*>(p)[1];
  union { u32x4 u; bf16x8 v; } r;
  r.u = (u32x4){pk2(f0.x, f0.y), pk2(f0.z, f0.w), pk2(f1.x, f1.y), pk2(f1.z, f1.w)};
  return r.v;
}
// tanh(x) = 1 - 2/(exp2(2*log2e*x)+1)
static __device__ __forceinline__ float fast_tanh(float x) {
  float e = __builtin_amdgcn_exp2f(x * 2.8853900817779268f);
  return 1.f - 2.f / (e + 1.f);
}

// ---- h staging (16 rows x 1024 cols bf16 = 32KB), split issue/finish ----
static __device__ __forceinline__ void stage_issue(const unsigned char* hb, int tid,
                                                   u32x4& s0, u32x4& s1,
                                                   u32x4& s2, u32x4& s3) {
  asm volatile("global_load_dwordx4 %0, %1, off sc0 sc1"
               : "=v"(s0) : "v"(hb + (size_t)(0 * 512 + tid) * 16) : "memory");
  asm volatile("global_load_dwordx4 %0, %1, off sc0 sc1"
               : "=v"(s1) : "v"(hb + (size_t)(1 * 512 + tid) * 16) : "memory");
  asm volatile("global_load_dwordx4 %0, %1, off sc0 sc1"
               : "=v"(s2) : "v"(hb + (size_t)(2 * 512 + tid) * 16) : "memory");
  asm volatile("global_load_dwordx4 %0, %1, off sc0 sc1"
               : "=v"(s3) : "v"(hb + (size_t)(3 * 512 + tid) * 16) : "memory");
}
static __device__ __forceinline__ void stage_finish(int tid, unsigned char* As,
                                                    u32x4 s0, u32x4 s1,
                                                    u32x4 s2, u32x4 s3) {
  asm volatile("s_waitcnt vmcnt(0)" ::: "memory");
  __builtin_amdgcn_sched_barrier(0);  // rule #18 fence
#define RNN_ST(J, SV)                                                           \
  {                                                                             \
    int id = (J) * 512 + tid;                                                   \
    int row = id >> 7, c = id & 127;                                            \
    *reinterpret_cast<u32x4*>(&As[row * 2048 + ((c ^ (row & 7)) << 4)]) = SV;   \
  }
  RNN_ST(0, s0) RNN_ST(1, s1) RNN_ST(2, s2) RNN_ST(3, s3)
#undef RNN_ST
}

// Poll the 16 flag words of one group (asm sc0 sc1 + rule-#18 fence).
static __device__ __forceinline__ void poll16(const unsigned* fl, unsigned tgt) {
  for (;;) {
    u32x4 a, b, c, d;
    asm volatile("global_load_dwordx4 %0, %1, off sc0 sc1" : "=v"(a) : "v"(fl) : "memory");
    asm volatile("global_load_dwordx4 %0, %1, off sc0 sc1" : "=v"(b) : "v"(fl + 4) : "memory");
    asm volatile("global_load_dwordx4 %0, %1, off sc0 sc1" : "=v"(c) : "v"(fl + 8) : "memory");
    asm volatile("global_load_dwordx4 %0, %1, off sc0 sc1" : "=v"(d) : "v"(fl + 12) : "memory");
    asm volatile("s_waitcnt vmcnt(0)" ::: "memory");
    __builtin_amdgcn_sched_barrier(0);  // rule #18 fence (the r6 bug)
    unsigned m = a.x;
    m = min(m, a.y); m = min(m, a.z); m = min(m, a.w);
    m = min(m, b.x); m = min(m, b.y); m = min(m, b.z); m = min(m, b.w);
    m = min(m, c.x); m = min(m, c.y); m = min(m, c.z); m = min(m, c.w);
    m = min(m, d.x); m = min(m, d.y); m = min(m, d.z); m = min(m, d.w);
    if (m >= tgt) return;
    __builtin_amdgcn_s_sleep(1);
  }
}

// ---------------------------------------------------------------------------
__global__ void prep_kernel(const float* __restrict__ seq,
                            unsigned short* __restrict__ seq_bf,
                            unsigned* __restrict__ flags) {
  size_t idx = (size_t)blockIdx.x * blockDim.x + threadIdx.x;
  size_t stride = (size_t)gridDim.x * blockDim.x;
  const size_t nchunk = (size_t)T_ * B_ * E_ / 8;
  for (size_t i = idx; i < nchunk; i += stride) {
    union { bf16x8 v; u32x4 u; } r;
    r.v = cvt8(seq + i * 8);
    *reinterpret_cast<u32x4*>(seq_bf + i * 8) = r.u;
  }
  if (idx < 1024) {
    unsigned z = 0;
    asm volatile("global_store_dword %0, %1, off sc0 sc1"
                 :: "v"(flags + idx), "v"(z) : "memory");
  }
}

// ---------------------------------------------------------------------------
__global__ __launch_bounds__(512, 4) void rnn_fused(
    const unsigned short* __restrict__ seq_bf, const float* __restrict__ Wh_w,
    const float* __restrict__ Wh_b, const float* __restrict__ Wi_w,
    const float* __restrict__ Wi_b, const float* __restrict__ Wo_w,
    const float* __restrict__ Wo_b,
    unsigned short* __restrict__ hbuf, unsigned* __restrict__ flags,
    float* __restrict__ out) {
  __shared__ __align__(16) unsigned char As[RG * 2048];  // 32 KB h tile (swizzled)
  __shared__ __align__(16) float red[2][RG][64];         // 8 KB k-split partials

  const int tid = threadIdx.x;
  const int bid = blockIdx.x;
  // bid and bid^256 map to different groups -> a CU's two resident blocks come
  // from independent groups under round-robin dispatch (and any-mapping stays
  // correct; pairing is a perf heuristic only).
  const int half = bid >> 8, idx = bid & 255;
  const int bm = ((idx & 15) << 1) | half;  // group 0..31
  const int bn = idx >> 4;                  // 0..15
  const int R0 = bm * RG, C0 = bn * 64;
  const int lane = tid & 63, wave = tid >> 6;
  const int wn = (wave & 3) * 16;  // n-offset in [0,64)
  const int wk = wave >> 2;        // k-split 0/1 (K-slice 512)
  const int l15 = lane & 15, k4 = lane >> 4;  // 16x16 frag: row/col=l15, k+=k4*8
  const int mycol = C0 + wn + l15;

  // ---- prologue: Wh / Wi fragments -> registers for all 128 steps
  bf16x8 bh[16];
  {
    const float* whp = Wh_w + (size_t)mycol * H_ + wk * 512 + k4 * 8;
#pragma unroll
    for (int ks = 0; ks < 16; ++ks) bh[ks] = cvt8(whp + ks * 32);
  }
  bf16x8 wif[4];
  {
    const float* wip = Wi_w + (size_t)mycol * E_ + wk * 128 + k4 * 8;
#pragma unroll
    for (int ks = 0; ks < 4; ++ks) wif[ks] = cvt8(wip + ks * 32);
  }
  // epilogue assignment: thread -> (erow, cols ec0, ec0+1)
  const int erow = tid >> 5, ec0 = (tid & 31) * 2;
  const float bias0 = Wh_b[C0 + ec0] + Wi_b[C0 + ec0];
  const float bias1 = Wh_b[C0 + ec0 + 1] + Wi_b[C0 + ec0 + 1];
  const unsigned* grpfl = flags + bm * 32;   // 128B-padded per group
  unsigned* myfl = flags + bm * 32 + bn;
  const size_t hoff_b = ((size_t)(R0 + erow) * H_ + C0 + ec0) * 2;  // bytes

  for (int t = 0; t < T_; ++t) {
    f32x4 acc = {0.f, 0.f, 0.f, 0.f};
    u32x4 s0, s1, s2, s3;
    if (t > 0) {
      // wait for the 16 producers of this group, then issue the h-tile loads
      poll16(grpfl, (unsigned)t);
      const unsigned char* hb =
          (const unsigned char*)(hbuf + (size_t)((t - 1) & 1) * HB) + (size_t)R0 * 2048;
      stage_issue(hb, tid, s0, s1, s2, s3);
    }
    // ---- x-part (independent of h) overlaps the staged loads in flight
    {
      const unsigned short* xp =
          seq_bf + ((size_t)t * B_ + R0 + l15) * E_ + wk * 128 + k4 * 8;
#pragma unroll
      for (int ks = 0; ks < 4; ++ks) {
        bf16x8 a = *reinterpret_cast<const bf16x8*>(xp + ks * 32);
        acc = __builtin_amdgcn_mfma_f32_16x16x32_bf16(a, wif[ks], acc, 0, 0, 0);
      }
    }
    if (t > 0) stage_finish(tid, As, s0, s1, s2, s3);
    __syncthreads();
    if (t > 0) {
      // ---- h-part: 16 MFMA over this wave's K-slice (Wh frags in regs)
#pragma unroll
      for (int ks = 0; ks < 16; ++ks) {
        int c = wk * 64 + ks * 4 + k4;
        bf16x8 a = *reinterpret_cast<const bf16x8*>(
            &As[l15 * 2048 + ((c ^ (l15 & 7)) << 4)]);
        acc = __builtin_amdgcn_mfma_f32_16x16x32_bf16(a, bh[ks], acc, 0, 0, 0);
      }
    }
    // ---- k-split partials (C layout: col=l15, row=k4*4+r)
#pragma unroll
    for (int r = 0; r < 4; ++r) red[wk][k4 * 4 + r][wn + l15] = acc[r];
    __syncthreads();
    // ---- distributed epilogue: each thread 2 outputs -> 4B store
    {
      f32x2 v0 = *reinterpret_cast<const f32x2*>(&red[0][erow][ec0]);
      f32x2 v1 = *reinterpret_cast<const f32x2*>(&red[1][erow][ec0]);
      float h0 = fast_tanh(v0[0] + v1[0] + bias0);
      float h1 = fast_tanh(v0[1] + v1[1] + bias1);
      unsigned pv = pk2(h0, h1);
      const unsigned char* dst =
          (const unsigned char*)hbuf + (size_t)(t & 1) * (HB * 2) + hoff_b;
      asm volatile("global_store_dword %0, %1, off sc0 sc1"
                   :: "v"(dst), "v"(pv) : "memory");
    }
    asm volatile("s_waitcnt vmcnt(0)" ::: "memory");  // h stores acked
    __syncthreads();
    if (tid == 0) {
      unsigned fv = (unsigned)(t + 1);
      asm volatile("global_store_dword %0, %1, off sc0 sc1"
                   :: "v"(myfl), "v"(fv) : "memory");
    }
  }

  // ---- final GEMM: out = h_T @ Wo^T + Wo_b (blocks bn<4, fp32 out)
  if (bn >= 4) return;
  {
    poll16(grpfl, (unsigned)T_);
    const unsigned char* hb =
        (const unsigned char*)(hbuf + (size_t)((T_ - 1) & 1) * HB) + (size_t)R0 * 2048;
    u32x4 s0, s1, s2, s3;
    stage_issue(hb, tid, s0, s1, s2, s3);
    stage_finish(tid, As, s0, s1, s2, s3);
    __syncthreads();
    f32x4 acc = {0.f, 0.f, 0.f, 0.f};
    const int oc = C0 + wn + l15;  // [0,256)
    const float* wop = Wo_w + (size_t)oc * H_ + wk * 512 + k4 * 8;
#pragma unroll
    for (int ks = 0; ks < 16; ++ks) {
      int c = wk * 64 + ks * 4 + k4;
      bf16x8 a = *reinterpret_cast<const bf16x8*>(
          &As[l15 * 2048 + ((c ^ (l15 & 7)) << 4)]);
      bf16x8 b = cvt8(wop + ks * 32);
      acc = __builtin_amdgcn_mfma_f32_16x16x32_bf16(a, b, acc, 0, 0, 0);
    }
#pragma unroll
    for (int r = 0; r < 4; ++r) red[wk][k4 * 4 + r][wn + l15] = acc[r];
    __syncthreads();
    {
      f32x2 v0 = *reinterpret_cast<const f32x2*>(&red[0][erow][ec0]);
      f32x2 v1 = *reinterpret_cast<const f32x2*>(&red[1][erow][ec0]);
      f32x2 o;
      o[0] = v0[0] + v1[0] + Wo_b[C0 + ec0];
      o[1] = v0[1] + v1[1] + Wo_b[C0 + ec0 + 1];
      *reinterpret_cast<f32x2*>(out + (size_t)(R0 + erow) * O_ + C0 + ec0) = o;
    }
  }
}

// ---------------------------------------------------------------------------
extern "C" void kernel_launch(void* const* d_in, const int* in_sizes, int n_in,
                              void* d_out, int out_size, void* d_ws, size_t ws_size,
                              hipStream_t stream) {
  const float* seq  = (const float*)d_in[0];
  const float* Wh_w = (const float*)d_in[1];
  const float* Wh_b = (const float*)d_in[2];
  const float* Wi_w = (const float*)d_in[3];
  const float* Wi_b = (const float*)d_in[4];
  const float* Wo_w = (const float*)d_in[5];
  const float* Wo_b = (const float*)d_in[6];

  char* ws = (char*)d_ws;
  unsigned short* hbuf   = (unsigned short*)ws; ws += (size_t)2 * HB * 2;  // 2 MB
  unsigned*       flags  = (unsigned*)ws;       ws += 4096;                // 32 x 128B
  unsigned short* seq_bf = (unsigned short*)ws;                            // 32 MB

  prep_kernel<<<2048, 256, 0, stream>>>(seq, seq_bf, flags);
  rnn_fused<<<512, 512, 0, stream>>>(seq_bf, Wh_w, Wh_b, Wi_w, Wi_b, Wo_w, Wo_b,
                                     hbuf, flags, (float*)d_out);
}

// Round 12
// 553.507 us; speedup vs baseline: 3.1810x; 3.1810x over previous
//
#include <hip/hip_runtime.h>
#include <hip/hip_bf16.h>

// Elman RNN, persistent kernel v9 — r5 geometry (best measured: 518us),
// per-wave fine-grained sync: 8-way k-split, each wave depends on only TWO
// producer blocks, stages its own 8KB h-slice, no stage barrier (2 barriers/step).
// h_t = tanh([h_{t-1} | x_t] @ [Wh|Wi]^T + (Wh_b+Wi_b)); out = h_T @ Wo^T + Wo_b
// T=128, B=512, E=256, H=1024, O=256.
//
// Measured laws driving this design:
//  r9/r10/r11: 1 block/CU lockstep beats every added-concurrency variant
//    (2 blocks/CU convoy + poll-spam contention; software 2-stream doubles LDS).
//  r2: RELEASE/agent atomics -> L2 writeback flush per step. Never.
//  r4/5/9: asm sc0 sc1 loads/stores: h+flags L2-served, FETCH ~107MB. Fast.
//  r6: asm load + waitcnt + register-only consumer needs sched_barrier(0).
//  r7/r8: compiler AGENT/SYSTEM atomic polls -> MALL/HBM storms. Never.
//
// Slot-overwrite safety: producer P overwrites slot s at step t+2 only after
// its 8 waves collectively polled ALL 16 group flags >= t+2 (union of per-wave
// pairs) and joined the block barrier; flag >= t+2 means every consumer already
// finished reading slot s at step t+1. The block-wide reduction barrier makes
// the union effective before the epilogue store.

#define T_ 128
#define B_ 512
#define E_ 256
#define H_ 1024
#define O_ 256
#define RG 32            // rows per group
#define HB (B_ * H_)     // elems per h slot (1 MB bf16)

typedef __bf16 bf16x8 __attribute__((ext_vector_type(8)));
typedef float  f32x4  __attribute__((ext_vector_type(4)));
typedef float  f32x16 __attribute__((ext_vector_type(16)));
typedef unsigned int u32x2 __attribute__((ext_vector_type(2)));
typedef unsigned int u32x4 __attribute__((ext_vector_type(4)));

static __device__ __forceinline__ unsigned short f2bf(float f) {
  unsigned u = __float_as_uint(f);
  u += 0x7fff + ((u >> 16) & 1);  // RNE
  return (unsigned short)(u >> 16);
}
static __device__ __forceinline__ unsigned pk2(float a, float b) {
  return (unsigned)f2bf(a) | ((unsigned)f2bf(b) << 16);
}
static __device__ __forceinline__ bf16x8 cvt8(const float* p) {
  float4 f0 = reinterpret_cast<const float4*>(p)[0];
  float4 f1 = reinterpret_cast<const float4*>(p)[1];
  union { u32x4 u; bf16x8 v; } r;
  r.u = (u32x4){pk2(f0.x, f0.y), pk2(f0.z, f0.w), pk2(f1.x, f1.y), pk2(f1.z, f1.w)};
  return r.v;
}
// tanh(x) = 1 - 2/(exp2(2*log2e*x)+1)
static __device__ __forceinline__ float fast_tanh(float x) {
  float e = __builtin_amdgcn_exp2f(x * 2.8853900817779268f);
  return 1.f - 2.f / (e + 1.f);
}

// Poll TWO flag words (this wave's producers) — one dwordx2 + rule-#18 fence.
static __device__ __forceinline__ void poll2(const unsigned* fl, unsigned tgt) {
  for (;;) {
    u32x2 a;
    asm volatile("global_load_dwordx2 %0, %1, off sc0 sc1"
                 : "=v"(a) : "v"(fl) : "memory");
    asm volatile("s_waitcnt vmcnt(0)" ::: "memory");
    __builtin_amdgcn_sched_barrier(0);  // rule #18 fence
    if (min(a.x, a.y) >= tgt) return;
    __builtin_amdgcn_s_sleep(1);
  }
}

// ---------------------------------------------------------------------------
__global__ void prep_kernel(const float* __restrict__ seq,
                            unsigned short* __restrict__ seq_bf,
                            unsigned* __restrict__ flags) {
  size_t idx = (size_t)blockIdx.x * blockDim.x + threadIdx.x;
  size_t stride = (size_t)gridDim.x * blockDim.x;
  const size_t nchunk = (size_t)T_ * B_ * E_ / 8;
  for (size_t i = idx; i < nchunk; i += stride) {
    union { bf16x8 v; u32x4 u; } r;
    r.v = cvt8(seq + i * 8);
    *reinterpret_cast<u32x4*>(seq_bf + i * 8) = r.u;
  }
  if (idx < 512) {
    unsigned z = 0;
    asm volatile("global_store_dword %0, %1, off sc0 sc1"
                 :: "v"(flags + idx), "v"(z) : "memory");
  }
}

// ---------------------------------------------------------------------------
__global__ __launch_bounds__(512, 2) void rnn_fused(
    const unsigned short* __restrict__ seq_bf, const float* __restrict__ Wh_w,
    const float* __restrict__ Wh_b, const float* __restrict__ Wi_w,
    const float* __restrict__ Wi_b, const float* __restrict__ Wo_w,
    const float* __restrict__ Wo_b,
    unsigned short* __restrict__ hbuf, unsigned* __restrict__ flags,
    float* __restrict__ out) {
  __shared__ __align__(16) unsigned char As[RG * 2048];  // 64 KB h tile (swizzled)
  __shared__ __align__(16) float red[8][32][68];         // 69.6 KB k-split partials

  const int tid = threadIdx.x;
  const int bid = blockIdx.x;
  const int bm = bid & 15, bn = bid >> 4;   // group 0..15 (32 rows), col-block 0..15
  const int R0 = bm * RG, C0 = bn * 64;
  const int lane = tid & 63, wv = tid >> 6; // wv = k-slice 0..7 (128 k each)
  const int l31 = lane & 31, k8 = lane >> 5;
  const int qr = lane >> 4, cl = lane & 15; // staging decomposition

  // ---- prologue: weight fragments -> registers for all 128 steps
  bf16x8 bh0[8], bh1[8];  // Wh cols C0+l31 / C0+32+l31, k-slice [wv*128,+128)
  {
    const float* p0 = Wh_w + (size_t)(C0 + l31) * H_ + wv * 128 + k8 * 8;
    const float* p1 = Wh_w + (size_t)(C0 + 32 + l31) * H_ + wv * 128 + k8 * 8;
#pragma unroll
    for (int ks = 0; ks < 8; ++ks) { bh0[ks] = cvt8(p0 + ks * 16); bh1[ks] = cvt8(p1 + ks * 16); }
  }
  bf16x8 wi0[2], wi1[2];  // Wi, x k-slice [wv*32,+32)
  {
    const float* p0 = Wi_w + (size_t)(C0 + l31) * E_ + wv * 32 + k8 * 8;
    const float* p1 = Wi_w + (size_t)(C0 + 32 + l31) * E_ + wv * 32 + k8 * 8;
#pragma unroll
    for (int ks = 0; ks < 2; ++ks) { wi0[ks] = cvt8(p0 + ks * 16); wi1[ks] = cvt8(p1 + ks * 16); }
  }
  // epilogue mapping: thread -> (erow, cols ec..ec+3); bias
  const int erow = tid >> 4, ec = (tid & 15) * 4;
  f32x4 bias4;
  {
    f32x4 b1 = *reinterpret_cast<const f32x4*>(Wh_b + C0 + ec);
    f32x4 b2 = *reinterpret_cast<const f32x4*>(Wi_b + C0 + ec);
    bias4 = b1 + b2;
  }
  const unsigned* grpfl = flags + bm * 32;        // 16 words per group (padded)
  const unsigned* wvfl = grpfl + wv * 2;          // this wave's 2 producers
  unsigned* myfl = flags + bm * 32 + bn;
  const size_t hoff_b = ((size_t)(R0 + erow) * H_ + C0 + ec) * 2;  // bytes

  for (int t = 0; t < T_; ++t) {
    f32x16 acc0 = 0, acc1 = 0;
    // ---- preload x fragments (no h dependence; latency overlaps poll)
    bf16x8 xa0, xa1;
    {
      const unsigned short* xp =
          seq_bf + ((size_t)t * B_ + R0 + l31) * E_ + wv * 32 + k8 * 8;
      xa0 = *reinterpret_cast<const bf16x8*>(xp);
      xa1 = *reinterpret_cast<const bf16x8*>(xp + 16);
    }
    u32x4 s0, s1, s2, s3, s4, s5, s6, s7;
    if (t > 0) {
      poll2(wvfl, (unsigned)t);  // only THIS wave's 2 producers
      // issue this wave's 8KB slice: rows 0..31, chunks c = wv*16 + cl
      const unsigned char* hb =
          (const unsigned char*)(hbuf + (size_t)((t - 1) & 1) * HB) + (size_t)R0 * 2048;
#define RNN_LD(J, SV)                                                             \
      asm volatile("global_load_dwordx4 %0, %1, off sc0 sc1"                      \
                   : "=v"(SV)                                                     \
                   : "v"(hb + (size_t)((J) * 4 + qr) * 2048 + (wv * 16 + cl) * 16)\
                   : "memory");
      RNN_LD(0, s0) RNN_LD(1, s1) RNN_LD(2, s2) RNN_LD(3, s3)
      RNN_LD(4, s4) RNN_LD(5, s5) RNN_LD(6, s6) RNN_LD(7, s7)
#undef RNN_LD
    }
    // ---- x-part: 4 MFMAs (k-slice 32 of E), overlaps stage loads in flight
    acc0 = __builtin_amdgcn_mfma_f32_32x32x16_bf16(xa0, wi0[0], acc0, 0, 0, 0);
    acc1 = __builtin_amdgcn_mfma_f32_32x32x16_bf16(xa0, wi1[0], acc1, 0, 0, 0);
    acc0 = __builtin_amdgcn_mfma_f32_32x32x16_bf16(xa1, wi0[1], acc0, 0, 0, 0);
    acc1 = __builtin_amdgcn_mfma_f32_32x32x16_bf16(xa1, wi1[1], acc1, 0, 0, 0);
    if (t > 0) {
      asm volatile("s_waitcnt vmcnt(0)" ::: "memory");
      __builtin_amdgcn_sched_barrier(0);  // rule #18 fence
      // write own slice to swizzled LDS (no other wave touches it)
#define RNN_ST(J, SV)                                                             \
      {                                                                           \
        int row = (J) * 4 + qr, c = wv * 16 + cl;                                 \
        *reinterpret_cast<u32x4*>(&As[row * 2048 + ((c ^ (row & 7)) << 4)]) = SV; \
      }
      RNN_ST(0, s0) RNN_ST(1, s1) RNN_ST(2, s2) RNN_ST(3, s3)
      RNN_ST(4, s4) RNN_ST(5, s5) RNN_ST(6, s6) RNN_ST(7, s7)
#undef RNN_ST
      asm volatile("s_waitcnt lgkmcnt(0)" ::: "memory");  // own writes visible
      __builtin_amdgcn_sched_barrier(0);
      // ---- h-part: 8 ks x 2 n MFMAs over own k-slice; NO barrier needed
#pragma unroll
      for (int ks = 0; ks < 8; ++ks) {
        int c = wv * 16 + ks * 2 + k8;
        bf16x8 a = *reinterpret_cast<const bf16x8*>(
            &As[l31 * 2048 + ((c ^ (l31 & 7)) << 4)]);
        acc0 = __builtin_amdgcn_mfma_f32_32x32x16_bf16(a, bh0[ks], acc0, 0, 0, 0);
        acc1 = __builtin_amdgcn_mfma_f32_32x32x16_bf16(a, bh1[ks], acc1, 0, 0, 0);
      }
    }
    // ---- k-split partials (C layout: col=l31, row=(r&3)+8*(r>>2)+4*k8)
#pragma unroll
    for (int r = 0; r < 16; ++r) {
      int gr = (r & 3) + 8 * (r >> 2) + 4 * k8;
      red[wv][gr][l31] = acc0[r];
      red[wv][gr][32 + l31] = acc1[r];
    }
    __syncthreads();  // barrier 1: all partials in
    // ---- distributed epilogue: sum 8 sources, bias, tanh, one 8B store
    {
      f32x4 v = *reinterpret_cast<const f32x4*>(&red[0][erow][ec]);
#pragma unroll
      for (int s = 1; s < 8; ++s)
        v += *reinterpret_cast<const f32x4*>(&red[s][erow][ec]);
      v += bias4;
      u32x2 pv = {pk2(fast_tanh(v[0]), fast_tanh(v[1])),
                  pk2(fast_tanh(v[2]), fast_tanh(v[3]))};
      const unsigned char* dst =
          (const unsigned char*)hbuf + (size_t)(t & 1) * (HB * 2) + hoff_b;
      asm volatile("global_store_dwordx2 %0, %1, off sc0 sc1"
                   :: "v"(dst), "v"(pv) : "memory");
    }
    asm volatile("s_waitcnt vmcnt(0)" ::: "memory");  // h stores acked
    __syncthreads();  // barrier 2: all stores drained before the flag
    if (tid == 0) {
      unsigned fv = (unsigned)(t + 1);
      asm volatile("global_store_dword %0, %1, off sc0 sc1"
                   :: "v"(myfl), "v"(fv) : "memory");
    }
  }

  // ---- final GEMM: out = h_T @ Wo^T + Wo_b (blocks bn<4 cover 512x256, fp32)
  if (bn >= 4) return;
  {
    poll2(wvfl, (unsigned)T_);  // per-wave slice dependency, same as main loop
    const unsigned char* hb =
        (const unsigned char*)(hbuf + (size_t)((T_ - 1) & 1) * HB) + (size_t)R0 * 2048;
    u32x4 s0, s1, s2, s3, s4, s5, s6, s7;
#define RNN_LD(J, SV)                                                             \
    asm volatile("global_load_dwordx4 %0, %1, off sc0 sc1"                        \
                 : "=v"(SV)                                                       \
                 : "v"(hb + (size_t)((J) * 4 + qr) * 2048 + (wv * 16 + cl) * 16)  \
                 : "memory");
    RNN_LD(0, s0) RNN_LD(1, s1) RNN_LD(2, s2) RNN_LD(3, s3)
    RNN_LD(4, s4) RNN_LD(5, s5) RNN_LD(6, s6) RNN_LD(7, s7)
#undef RNN_LD
    asm volatile("s_waitcnt vmcnt(0)" ::: "memory");
    __builtin_amdgcn_sched_barrier(0);
#define RNN_ST(J, SV)                                                             \
    {                                                                             \
      int row = (J) * 4 + qr, c = wv * 16 + cl;                                   \
      *reinterpret_cast<u32x4*>(&As[row * 2048 + ((c ^ (row & 7)) << 4)]) = SV;   \
    }
    RNN_ST(0, s0) RNN_ST(1, s1) RNN_ST(2, s2) RNN_ST(3, s3)
    RNN_ST(4, s4) RNN_ST(5, s5) RNN_ST(6, s6) RNN_ST(7, s7)
#undef RNN_ST
    asm volatile("s_waitcnt lgkmcnt(0)" ::: "memory");
    __builtin_amdgcn_sched_barrier(0);
    f32x16 acc0 = 0, acc1 = 0;
    const float* w0 = Wo_w + (size_t)(C0 + l31) * H_ + wv * 128 + k8 * 8;
    const float* w1 = Wo_w + (size_t)(C0 + 32 + l31) * H_ + wv * 128 + k8 * 8;
#pragma unroll
    for (int ks = 0; ks < 8; ++ks) {
      int c = wv * 16 + ks * 2 + k8;
      bf16x8 a = *reinterpret_cast<const bf16x8*>(
          &As[l31 * 2048 + ((c ^ (l31 & 7)) << 4)]);
      acc0 = __builtin_amdgcn_mfma_f32_32x32x16_bf16(a, cvt8(w0 + ks * 16), acc0, 0, 0, 0);
      acc1 = __builtin_amdgcn_mfma_f32_32x32x16_bf16(a, cvt8(w1 + ks * 16), acc1, 0, 0, 0);
    }
#pragma unroll
    for (int r = 0; r < 16; ++r) {
      int gr = (r & 3) + 8 * (r >> 2) + 4 * k8;
      red[wv][gr][l31] = acc0[r];
      red[wv][gr][32 + l31] = acc1[r];
    }
    __syncthreads();
    {
      f32x4 v = *reinterpret_cast<const f32x4*>(&red[0][erow][ec]);
#pragma unroll
      for (int s = 1; s < 8; ++s)
        v += *reinterpret_cast<const f32x4*>(&red[s][erow][ec]);
      v += *reinterpret_cast<const f32x4*>(Wo_b + C0 + ec);
      *reinterpret_cast<f32x4*>(out + (size_t)(R0 + erow) * O_ + C0 + ec) = v;
    }
  }
}

// ---------------------------------------------------------------------------
extern "C" void kernel_launch(void* const* d_in, const int* in_sizes, int n_in,
                              void* d_out, int out_size, void* d_ws, size_t ws_size,
                              hipStream_t stream) {
  const float* seq  = (const float*)d_in[0];
  const float* Wh_w = (const float*)d_in[1];
  const float* Wh_b = (const float*)d_in[2];
  const float* Wi_w = (const float*)d_in[3];
  const float* Wi_b = (const float*)d_in[4];
  const float* Wo_w = (const float*)d_in[5];
  const float* Wo_b = (const float*)d_in[6];

  char* ws = (char*)d_ws;
  unsigned short* hbuf   = (unsigned short*)ws; ws += (size_t)2 * HB * 2;  // 2 MB
  unsigned*       flags  = (unsigned*)ws;       ws += 4096;                // 16 x 128B
  unsigned short* seq_bf = (unsigned short*)ws;                            // 32 MB

  prep_kernel<<<2048, 256, 0, stream>>>(seq, seq_bf, flags);
  rnn_fused<<<256, 512, 0, stream>>>(seq_bf, Wh_w, Wh_b, Wi_w, Wi_b, Wo_w, Wo_b,
                                     hbuf, flags, (float*)d_out);
}

// Round 13
// 453.319 us; speedup vs baseline: 3.8841x; 1.2210x over previous
//
#include <hip/hip_runtime.h>
#include <hip/hip_bf16.h>

// Elman RNN, persistent kernel v10 — 32 groups x 16 rows x 8 blocks(128 cols),
// per-wave SINGLE-producer sync (minimal possible), padded-LDS staging.
// h_t = tanh([h_{t-1} | x_t] @ [Wh|Wi]^T + (Wh_b+Wi_b)); out = h_T @ Wo^T + Wo_b
// T=128, B=512, E=256, H=1024, O=256.
//
// Measured laws:
//  r9/r10/r11: 1 block/CU lockstep beats all added-concurrency variants.
//  r2: RELEASE/agent atomics -> L2 writeback flush. Never.
//  r4/5/9/12: asm sc0 sc1 loads/stores: h+flags local-L2-served, FETCH ~107MB.
//  r6: asm load + waitcnt + register-only consumer needs sched_barrier(0).
//  r7/r8: compiler AGENT/SYSTEM atomic polls -> MALL/HBM storms. Never.
//  r12: per-wave fine sync works; group-16 convoy + 16x h re-read = residue.
//
// Slot-overwrite safety: block P's epilogue store of h_{t+2} (slot t&1) happens
// after P's barrier1 at step t+2, which joins 8 waves that each polled a
// DISTINCT producer flag >= t+2 (waves 0..7 poll producers 0..7 = the whole
// group). flag[j] >= t+2 means block j finished step t+1, i.e. finished
// READING h_t. So every reader of slot t&1 is done before the overwrite.

#define T_ 128
#define B_ 512
#define E_ 256
#define H_ 1024
#define O_ 256
#define RG 16            // rows per group
#define HB (B_ * H_)     // elems per h slot (1 MB bf16)
#define ROWB 2064        // LDS row stride bytes (2048 + 16 pad: bank-balanced)

typedef __bf16 bf16x8 __attribute__((ext_vector_type(8)));
typedef float  f32x4  __attribute__((ext_vector_type(4)));
typedef unsigned int u32x2 __attribute__((ext_vector_type(2)));
typedef unsigned int u32x4 __attribute__((ext_vector_type(4)));

static __device__ __forceinline__ unsigned short f2bf(float f) {
  unsigned u = __float_as_uint(f);
  u += 0x7fff + ((u >> 16) & 1);  // RNE
  return (unsigned short)(u >> 16);
}
static __device__ __forceinline__ unsigned pk2(float a, float b) {
  return (unsigned)f2bf(a) | ((unsigned)f2bf(b) << 16);
}
static __device__ __forceinline__ bf16x8 cvt8(const float* p) {
  float4 f0 = reinterpret_cast<const float4*>(p)[0];
  float4 f1 = reinterpret_cast<const float4*>(p)[1];
  union { u32x4 u; bf16x8 v; } r;
  r.u = (u32x4){pk2(f0.x, f0.y), pk2(f0.z, f0.w), pk2(f1.x, f1.y), pk2(f1.z, f1.w)};
  return r.v;
}
// tanh(x) = 1 - 2/(exp2(2*log2e*x)+1)
static __device__ __forceinline__ float fast_tanh(float x) {
  float e = __builtin_amdgcn_exp2f(x * 2.8853900817779268f);
  return 1.f - 2.f / (e + 1.f);
}

// Poll ONE flag word (this wave's single producer) + rule-#18 fence.
static __device__ __forceinline__ void poll1(const unsigned* fl, unsigned tgt) {
  for (;;) {
    unsigned a;
    asm volatile("global_load_dword %0, %1, off sc0 sc1"
                 : "=v"(a) : "v"(fl) : "memory");
    asm volatile("s_waitcnt vmcnt(0)" ::: "memory");
    __builtin_amdgcn_sched_barrier(0);  // rule #18 fence
    if (a >= tgt) return;
    __builtin_amdgcn_s_sleep(1);
  }
}

// ---------------------------------------------------------------------------
__global__ void prep_kernel(const float* __restrict__ seq,
                            unsigned short* __restrict__ seq_bf,
                            unsigned* __restrict__ flags) {
  size_t idx = (size_t)blockIdx.x * blockDim.x + threadIdx.x;
  size_t stride = (size_t)gridDim.x * blockDim.x;
  const size_t nchunk = (size_t)T_ * B_ * E_ / 8;
  for (size_t i = idx; i < nchunk; i += stride) {
    union { bf16x8 v; u32x4 u; } r;
    r.v = cvt8(seq + i * 8);
    *reinterpret_cast<u32x4*>(seq_bf + i * 8) = r.u;
  }
  if (idx < 1024) {
    unsigned z = 0;
    asm volatile("global_store_dword %0, %1, off sc0 sc1"
                 :: "v"(flags + idx), "v"(z) : "memory");
  }
}

// ---------------------------------------------------------------------------
__global__ __launch_bounds__(512, 2) void rnn_fused(
    const unsigned short* __restrict__ seq_bf, const float* __restrict__ Wh_w,
    const float* __restrict__ Wh_b, const float* __restrict__ Wi_w,
    const float* __restrict__ Wi_b, const float* __restrict__ Wo_w,
    const float* __restrict__ Wo_b,
    unsigned short* __restrict__ hbuf, unsigned* __restrict__ flags,
    float* __restrict__ out) {
  __shared__ __align__(16) unsigned char As[RG * ROWB];  // 33 KB h tile (padded)
  __shared__ __align__(16) float red[8][RG][132];        // 67.6 KB k-split partials

  const int tid = threadIdx.x;
  const int bid = blockIdx.x;
  // group g: 8 blocks at bids {g, g+32, ..., g+224} -> all == g (mod 8): same XCD.
  const int g = bid & 31, p = bid >> 5;   // group 0..31, producer-index 0..7
  const int R0 = g * RG, C0 = p * 128;
  const int lane = tid & 63, wv = tid >> 6;   // wv = k-slice index 0..7
  const int l15 = lane & 15, k4 = lane >> 4;  // frag coords: row=l15, kchunk+=k4
  const int srow = lane >> 2, scc = lane & 3; // staging coords (64B-coalesced)

  // ---- prologue: weight fragments -> registers for all 128 steps
  bf16x8 bh[8][4];  // Wh[C0+nn*16+l15][wv*128 + (ks*4+k4)*8 ..+8] : 128 VGPR
#pragma unroll
  for (int nn = 0; nn < 8; ++nn) {
    const float* wp = Wh_w + (size_t)(C0 + nn * 16 + l15) * H_ + wv * 128 + k4 * 8;
#pragma unroll
    for (int ks = 0; ks < 4; ++ks) bh[nn][ks] = cvt8(wp + ks * 32);
  }
  bf16x8 wif[8];    // Wi[C0+nn*16+l15][wv*32 + k4*8 ..+8] : 32 VGPR
#pragma unroll
  for (int nn = 0; nn < 8; ++nn)
    wif[nn] = cvt8(Wi_w + (size_t)(C0 + nn * 16 + l15) * E_ + wv * 32 + k4 * 8);

  // epilogue mapping: thread -> (erow, cols ec..ec+3)
  const int erow = tid >> 5, ec = (tid & 31) * 4;
  f32x4 bias4;
  {
    f32x4 b1 = *reinterpret_cast<const f32x4*>(Wh_b + C0 + ec);
    f32x4 b2 = *reinterpret_cast<const f32x4*>(Wi_b + C0 + ec);
    bias4 = b1 + b2;
  }
  const unsigned* wvfl = flags + g * 32 + wv;  // this wave's single producer
  unsigned* myfl = flags + g * 32 + p;
  const size_t hoff_b = ((size_t)(R0 + erow) * H_ + C0 + ec) * 2;  // bytes

  for (int t = 0; t < T_; ++t) {
    f32x4 acc[8];
#pragma unroll
    for (int nn = 0; nn < 8; ++nn) acc[nn] = (f32x4){0.f, 0.f, 0.f, 0.f};
    // ---- x a-frag (no h dependence; load issues before/while polling)
    bf16x8 xa = *reinterpret_cast<const bf16x8*>(
        seq_bf + ((size_t)t * B_ + R0 + l15) * E_ + wv * 32 + k4 * 8);
    u32x4 s0, s1, s2, s3;
    if (t > 0) {
      poll1(wvfl, (unsigned)t);  // ONE producer: block wv of this group
      // issue own 4KB slice: rows 0..15, cols [wv*128,+128); 64B/4-lane runs
      const unsigned char* hb =
          (const unsigned char*)(hbuf + (size_t)((t - 1) & 1) * HB) +
          (size_t)R0 * 2048 + wv * 256;
#define RNN_LD(J, SV)                                                            \
      asm volatile("global_load_dwordx4 %0, %1, off sc0 sc1"                     \
                   : "=v"(SV)                                                    \
                   : "v"(hb + (size_t)srow * 2048 + ((J) * 4 + scc) * 16)        \
                   : "memory");
      RNN_LD(0, s0) RNN_LD(1, s1) RNN_LD(2, s2) RNN_LD(3, s3)
#undef RNN_LD
    }
    // ---- x-part: 8 MFMAs (k-slice 32 of E) overlap the stage loads
#pragma unroll
    for (int nn = 0; nn < 8; ++nn)
      acc[nn] = __builtin_amdgcn_mfma_f32_16x16x32_bf16(xa, wif[nn], acc[nn], 0, 0, 0);
    if (t > 0) {
      asm volatile("s_waitcnt vmcnt(0)" ::: "memory");
      __builtin_amdgcn_sched_barrier(0);  // rule #18 fence
      // own slice -> padded LDS window chunks [wv*16,+16)
#define RNN_ST(J, SV)                                                            \
      *reinterpret_cast<u32x4*>(                                                 \
          &As[srow * ROWB + (wv * 16 + (J) * 4 + scc) * 16]) = SV;
      RNN_ST(0, s0) RNN_ST(1, s1) RNN_ST(2, s2) RNN_ST(3, s3)
#undef RNN_ST
      asm volatile("s_waitcnt lgkmcnt(0)" ::: "memory");  // own writes visible
      __builtin_amdgcn_sched_barrier(0);
      // ---- h-part: 4 ks x 8 n MFMAs over own k-slice (no barrier: self-staged)
#pragma unroll
      for (int ks = 0; ks < 4; ++ks) {
        bf16x8 a = *reinterpret_cast<const bf16x8*>(
            &As[l15 * ROWB + (wv * 16 + ks * 4 + k4) * 16]);
#pragma unroll
        for (int nn = 0; nn < 8; ++nn)
          acc[nn] = __builtin_amdgcn_mfma_f32_16x16x32_bf16(a, bh[nn][ks], acc[nn], 0, 0, 0);
      }
    }
    // ---- k-split partials (C layout: col=l15, row=k4*4+r)
#pragma unroll
    for (int nn = 0; nn < 8; ++nn)
#pragma unroll
      for (int r = 0; r < 4; ++r)
        red[wv][k4 * 4 + r][nn * 16 + l15] = acc[nn][r];
    __syncthreads();  // barrier 1: partials in
    // ---- distributed epilogue: 4 cols/thread, 8-source reduce, tanh, 8B store
    {
      f32x4 v = *reinterpret_cast<const f32x4*>(&red[0][erow][ec]);
#pragma unroll
      for (int s = 1; s < 8; ++s)
        v += *reinterpret_cast<const f32x4*>(&red[s][erow][ec]);
      v += bias4;
      u32x2 pv = {pk2(fast_tanh(v[0]), fast_tanh(v[1])),
                  pk2(fast_tanh(v[2]), fast_tanh(v[3]))};
      const unsigned char* dst =
          (const unsigned char*)hbuf + (size_t)(t & 1) * (HB * 2) + hoff_b;
      asm volatile("global_store_dwordx2 %0, %1, off sc0 sc1"
                   :: "v"(dst), "v"(pv) : "memory");
    }
    asm volatile("s_waitcnt vmcnt(0)" ::: "memory");  // h stores acked
    __syncthreads();  // barrier 2: all stores drained before the flag
    if (tid == 0) {
      unsigned fv = (unsigned)(t + 1);
      asm volatile("global_store_dword %0, %1, off sc0 sc1"
                   :: "v"(myfl), "v"(fv) : "memory");
    }
  }

  // ---- final GEMM: out = h_T @ Wo^T + Wo_b (blocks p<2 cover 512x256, fp32)
  if (p >= 2) return;
  {
    poll1(wvfl, (unsigned)T_);
    const unsigned char* hb =
        (const unsigned char*)(hbuf + (size_t)((T_ - 1) & 1) * HB) +
        (size_t)R0 * 2048 + wv * 256;
    u32x4 s0, s1, s2, s3;
#define RNN_LD(J, SV)                                                            \
    asm volatile("global_load_dwordx4 %0, %1, off sc0 sc1"                       \
                 : "=v"(SV)                                                      \
                 : "v"(hb + (size_t)srow * 2048 + ((J) * 4 + scc) * 16)          \
                 : "memory");
    RNN_LD(0, s0) RNN_LD(1, s1) RNN_LD(2, s2) RNN_LD(3, s3)
#undef RNN_LD
    asm volatile("s_waitcnt vmcnt(0)" ::: "memory");
    __builtin_amdgcn_sched_barrier(0);
#define RNN_ST(J, SV)                                                            \
    *reinterpret_cast<u32x4*>(                                                   \
        &As[srow * ROWB + (wv * 16 + (J) * 4 + scc) * 16]) = SV;
    RNN_ST(0, s0) RNN_ST(1, s1) RNN_ST(2, s2) RNN_ST(3, s3)
#undef RNN_ST
    asm volatile("s_waitcnt lgkmcnt(0)" ::: "memory");
    __builtin_amdgcn_sched_barrier(0);
    f32x4 acc[8];
#pragma unroll
    for (int nn = 0; nn < 8; ++nn) acc[nn] = (f32x4){0.f, 0.f, 0.f, 0.f};
#pragma unroll
    for (int ks = 0; ks < 4; ++ks) {
      bf16x8 a = *reinterpret_cast<const bf16x8*>(
          &As[l15 * ROWB + (wv * 16 + ks * 4 + k4) * 16]);
#pragma unroll
      for (int nn = 0; nn < 8; ++nn) {
        bf16x8 b = cvt8(Wo_w + (size_t)(C0 + nn * 16 + l15) * H_ +
                        wv * 128 + ks * 32 + k4 * 8);
        acc[nn] = __builtin_amdgcn_mfma_f32_16x16x32_bf16(a, b, acc[nn], 0, 0, 0);
      }
    }
#pragma unroll
    for (int nn = 0; nn < 8; ++nn)
#pragma unroll
      for (int r = 0; r < 4; ++r)
        red[wv][k4 * 4 + r][nn * 16 + l15] = acc[nn][r];
    __syncthreads();
    {
      f32x4 v = *reinterpret_cast<const f32x4*>(&red[0][erow][ec]);
#pragma unroll
      for (int s = 1; s < 8; ++s)
        v += *reinterpret_cast<const f32x4*>(&red[s][erow][ec]);
      v += *reinterpret_cast<const f32x4*>(Wo_b + C0 + ec);
      *reinterpret_cast<f32x4*>(out + (size_t)(R0 + erow) * O_ + C0 + ec) = v;
    }
  }
}

// ---------------------------------------------------------------------------
extern "C" void kernel_launch(void* const* d_in, const int* in_sizes, int n_in,
                              void* d_out, int out_size, void* d_ws, size_t ws_size,
                              hipStream_t stream) {
  const float* seq  = (const float*)d_in[0];
  const float* Wh_w = (const float*)d_in[1];
  const float* Wh_b = (const float*)d_in[2];
  const float* Wi_w = (const float*)d_in[3];
  const float* Wi_b = (const float*)d_in[4];
  const float* Wo_w = (const float*)d_in[5];
  const float* Wo_b = (const float*)d_in[6];

  char* ws = (char*)d_ws;
  unsigned short* hbuf   = (unsigned short*)ws; ws += (size_t)2 * HB * 2;  // 2 MB
  unsigned*       flags  = (unsigned*)ws;       ws += 4096;                // 32 x 128B
  unsigned short* seq_bf = (unsigned short*)ws;                            // 32 MB

  prep_kernel<<<2048, 256, 0, stream>>>(seq, seq_bf, flags);
  rnn_fused<<<256, 512, 0, stream>>>(seq_bf, Wh_w, Wh_b, Wi_w, Wi_b, Wo_w, Wo_b,
                                     hbuf, flags, (float*)d_out);
}